// Round 19
// baseline (29.008 us; speedup 1.0000x reference)
//
#include <hip/hip_runtime.h>

// Post_process_deconv: out = depth + b + sum_k w[k] * (weight[k] - mean_k(weight)) *
//                           bilinear(depth, y - 1 + kh + dy_k, x - 1 + kw + dx_k)
// Shapes: depth [B,1,H,W], weight [B,9,H,W], offset [B,18,H,W], w [1,1,3,3], b [1]
// B=2, H=352, W=1216, K=3, pad=1. All fp32.
//
// Round 19 = round 18 (TY=8 tile, row-pair LDS, pre-barrier address math,
// XCD-bijective chunk swizzle, nontemporal streams, rare exact fixup) with
// ONE change: __launch_bounds__(512, 8) -> 8 waves/SIMD floor = 4 blocks/CU
// resident (was 2 at (512,4)), VGPR cap 64 (natural alloc 40-52, no spill
// expected). Doubles the TLP covering the stage->barrier->tap latency chain.

#define KK 3
#define K2 9
#define PAD 1
#define BB 2
#define HH 352
#define WW 1216

#define TX 64                       // tile width  (19 tiles)
#define TY 8                        // tile height (44 tiles)
#define NTX (WW / TX)               // 19
#define NTY (HH / TY)               // 44
#define TILES (NTY * NTX)           // 836 per batch
#define NBLK (BB * TILES)           // 1672 = 8 * 209
#define CHUNK (NBLK / 8)            // 209
#define NTHR 512
#define HALO 7
#define SROWS (TY + 2 * HALO + 1)   // 23 raw rows
#define PROWS (SROWS - 1)           // 22 packed row-pair rows
#define SCOLS (TX + 2 * HALO + 2)   // 80
#define PN (PROWS * SCOLS)          // 1760 packed entries
#define NSTG ((PN + NTHR - 1) / NTHR)   // 4
#define NPAIR (PN / 2)              // 880 float4 slots
#define NPI ((NPAIR + NTHR - 1) / NTHR) // 2 interior iterations

__global__ __launch_bounds__(NTHR, 8) void ppd_kernel(
    const float* __restrict__ depth,   // [B, H*W]
    const float* __restrict__ weight,  // [B, 9, H*W]
    const float* __restrict__ offset,  // [B, 18, H*W]
    const float* __restrict__ wk,      // [9]
    const float* __restrict__ bias,    // [1]
    float* __restrict__ out)           // [B, H*W]
{
    constexpr int HW = HH * WW;

    __shared__ float2 pd[PN];           // 14080 B

    // bijective XCD-chunked swizzle (1672 % 8 == 0)
    const int bid0 = blockIdx.x;
    const int bid  = (bid0 & 7) * CHUNK + (bid0 >> 3);

    const int b   = bid / TILES;
    const int rem = bid - b * TILES;
    const int ty  = rem / NTX;
    const int tx  = rem - ty * NTX;

    const int tid = threadIdx.x;
    const int lx  = tid & (TX - 1);
    const int lyq = tid >> 6;             // 0..7
    const int x   = tx * TX + lx;
    const int y   = ty * TY + lyq;

    const float* dimg = depth + (size_t)b * HW;
    const int base_y = ty * TY - HALO;
    const int base_x = tx * TX - HALO;

    // interior: all raw rows [base_y, base_y+22] and cols [base_x, base_x+79]
    // in-image. base_y >= 0 <=> ty >= 1; base_y+22 <= 351 <=> ty <= 42.
    const bool interior = (ty >= 1) & (ty <= 42) & (tx >= 1) & (tx <= 17);

    // ---- staging phase A: global loads to registers ----
    float2 fa[NPI], fb[NPI];            // interior regs
    float2 stg[NSTG];                   // boundary regs
    if (interior) {
#pragma unroll
        for (int i = 0; i < NPI; ++i) {
            const int s = tid + i * NTHR;       // pair-slot 0..879
            const int e = 2 * s;                // even entry
            const int r = e / SCOLS;
            const int c = e - r * SCOLS;
            const float* p0 = dimg + (base_y + r)     * WW + base_x + c;
            const float* p1 = dimg + (base_y + r + 1) * WW + base_x + c;
            if (s < NPAIR) {
                __builtin_memcpy(&fa[i], p0, 8);
                __builtin_memcpy(&fb[i], p1, 8);
            }
        }
    } else {
#pragma unroll
        for (int i = 0; i < NSTG; ++i) {
            const int t = tid + i * NTHR;
            const int r = t / SCOLS;
            const int c = t - r * SCOLS;
            const int gy = base_y + r;
            const int gx = base_x + c;
            float a = 0.f, bb2 = 0.f;
            const bool gxok = ((unsigned)gx < (unsigned)WW) && (t < PN);
            if (gxok && (unsigned)gy < (unsigned)HH)       a   = dimg[gy * WW + gx];
            if (gxok && (unsigned)(gy + 1) < (unsigned)HH) bb2 = dimg[(gy + 1) * WW + gx];
            stg[i] = make_float2(a, bb2);
        }
    }

    // ---- streaming plane loads (single-use -> nontemporal) ----
    const int hw = y * WW + x;
    const float* wgt = weight + (size_t)b * (K2 * HW) + hw;
    const float* off = offset + (size_t)b * (2 * K2 * HW) + hw;

    float dyv[K2], dxv[K2], wv[K2];
#pragma unroll
    for (int k = 0; k < K2; ++k) {
        dyv[k] = __builtin_nontemporal_load(&off[(2 * k)     * HW]);
        dxv[k] = __builtin_nontemporal_load(&off[(2 * k + 1) * HW]);
    }
#pragma unroll
    for (int k = 0; k < K2; ++k) wv[k] = __builtin_nontemporal_load(&wgt[k * HW]);

    // ---- staging phase B: LDS writes (waits staging loads only) ----
    if (interior) {
#pragma unroll
        for (int i = 0; i < NPI; ++i) {
            const int s = tid + i * NTHR;
            if (s < NPAIR) {
                float4 q = make_float4(fa[i].x, fb[i].x, fa[i].y, fb[i].y);
                *reinterpret_cast<float4*>(&pd[2 * s]) = q;
            }
        }
    } else {
#pragma unroll
        for (int i = 0; i < NSTG; ++i) {
            const int t = tid + i * NTHR;
            if (t < PN) pd[t] = stg[i];
        }
    }

    // ---- PRE-BARRIER: tap addresses + fracs + miss bits + wsum ----
    int   ta[K2];
    float fyv[K2], fxv[K2];
    unsigned miss = 0u;
#pragma unroll
    for (int k = 0; k < K2; ++k) {
        const int kh = k / KK;
        const int kw = k - kh * KK;
        const float py = (float)(y - PAD + kh) + dyv[k];
        const float px = (float)(x - PAD + kw) + dxv[k];
        const float y0f = floorf(py);
        const float x0f = floorf(px);
        fyv[k] = py - y0f;
        fxv[k] = px - x0f;
        const int y0 = (int)y0f;
        const int x0 = (int)x0f;
        const int lr = y0 - base_y;
        const int lc = x0 - base_x;
        const int lrc = min(max(lr, 0), PROWS - 1);
        const int lcc = min(max(lc, 0), SCOLS - 2);
        const bool ok = ((unsigned)lr <= (unsigned)(PROWS - 1)) &
                        ((unsigned)lc <= (unsigned)(SCOLS - 2));
        miss |= ok ? 0u : (1u << k);
        ta[k] = lrc * SCOLS + lcc;
    }

    float wsum = 0.f;
#pragma unroll
    for (int k = 0; k < K2; ++k) wsum += wv[k];
    const float wmean = wsum * (1.0f / 9.0f);

    __syncthreads();

    // ---- POST-BARRIER: all corner-pair reads back-to-back, then lerps ----
    float2 c0[K2], c1[K2];
#pragma unroll
    for (int k = 0; k < K2; ++k) {
        c0[k] = pd[ta[k]];          // (v00, v10)
        c1[k] = pd[ta[k] + 1];      // (v01, v11)
    }

    float acc = 0.f;
#pragma unroll
    for (int k = 0; k < K2; ++k) {
        const float fy = fyv[k];
        const float fx = fxv[k];
        const float s = (1.f - fy) * ((1.f - fx) * c0[k].x + fx * c1[k].x)
                      + fy         * ((1.f - fx) * c0[k].y + fx * c1[k].y);
        acc = fmaf(wk[k] * (wv[k] - wmean), s, acc);
    }

    // ---- rare exact fixup for taps outside the staged halo ----
    if (miss) {
#pragma unroll 1
        for (int k = 0; k < K2; ++k) {
            if (!(miss & (1u << k))) continue;
            const int kh = k / KK;
            const int kw = k - kh * KK;
            const float dy = off[(2 * k)     * HW];
            const float dx = off[(2 * k + 1) * HW];
            const float wvk = wgt[k * HW];
            const float py = (float)(y - PAD + kh) + dy;
            const float px = (float)(x - PAD + kw) + dx;
            const float y0f = floorf(py);
            const float x0f = floorf(px);
            const float fy = py - y0f;
            const float fx = px - x0f;
            const int y0 = (int)y0f;
            const int x0 = (int)x0f;

            // recompute the (wrong) fast-path sample exactly as above
            const int lrc = min(max(y0 - base_y, 0), PROWS - 1);
            const int lcc = min(max(x0 - base_x, 0), SCOLS - 2);
            const float2 e0 = pd[lrc * SCOLS + lcc];
            const float2 e1 = pd[lrc * SCOLS + lcc + 1];
            const float sf = (1.f - fy) * ((1.f - fx) * e0.x + fx * e1.x)
                           + fy         * ((1.f - fx) * e0.y + fx * e1.y);

            // true sample via global clamped loads + validity-folded weights
            const float wy0 = ((unsigned)y0       < (unsigned)HH) ? (1.f - fy) : 0.f;
            const float wy1 = ((unsigned)(y0 + 1) < (unsigned)HH) ? fy         : 0.f;
            const float wx0 = ((unsigned)x0       < (unsigned)WW) ? (1.f - fx) : 0.f;
            const float wx1 = ((unsigned)(x0 + 1) < (unsigned)WW) ? fx         : 0.f;
            const int y0c = min(max(y0, 0), HH - 1);
            const int y1c = min(max(y0 + 1, 0), HH - 1);
            const int x0c = min(max(x0, 0), WW - 1);
            const int x1c = min(max(x0 + 1, 0), WW - 1);
            const float st = wy0 * (wx0 * dimg[y0c * WW + x0c] + wx1 * dimg[y0c * WW + x1c])
                           + wy1 * (wx0 * dimg[y1c * WW + x0c] + wx1 * dimg[y1c * WW + x1c]);

            acc = fmaf(wk[k] * (wvk - wmean), st - sf, acc);
        }
    }

    // residual from LDS; epilogue (nontemporal store — single-use)
    const float dres = pd[(y - base_y) * SCOLS + (x - base_x)].x;
    __builtin_nontemporal_store(acc + bias[0] + dres, &out[(size_t)b * HW + hw]);
}

extern "C" void kernel_launch(void* const* d_in, const int* in_sizes, int n_in,
                              void* d_out, int out_size, void* d_ws, size_t ws_size,
                              hipStream_t stream) {
    const float* depth  = (const float*)d_in[0];
    const float* weight = (const float*)d_in[1];
    const float* offset = (const float*)d_in[2];
    const float* wk     = (const float*)d_in[3];
    const float* bias   = (const float*)d_in[4];
    float* out = (float*)d_out;

    ppd_kernel<<<NBLK, NTHR, 0, stream>>>(depth, weight, offset, wk, bias, out);
}

// Round 20
// 20.290 us; speedup vs baseline: 1.4297x; 1.4297x over previous
//
#include <hip/hip_runtime.h>

// Post_process_deconv: out = depth + b + sum_k w[k] * (weight[k] - mean_k(weight)) *
//                           bilinear(depth, y - 1 + kh + dy_k, x - 1 + kw + dx_k)
// Shapes: depth [B,1,H,W], weight [B,9,H,W], offset [B,18,H,W], w [1,1,3,3], b [1]
// B=2, H=352, W=1216, K=3, pad=1. All fp32.
//
// Round 20 = round 18 (TY=8 tile, row-pair LDS, pre-barrier address math,
// XCD-bijective chunk swizzle, nontemporal streams, rare exact fixup) with
// __launch_bounds__(512, 6): VGPR cap ~85 (natural alloc ~75-90, minimal
// binding), 3 blocks/CU resident (was 2 at (512,4); (512,8)'s cap-64 spilled
// and regressed to 29us). Final test of the TLP axis.

#define KK 3
#define K2 9
#define PAD 1
#define BB 2
#define HH 352
#define WW 1216

#define TX 64                       // tile width  (19 tiles)
#define TY 8                        // tile height (44 tiles)
#define NTX (WW / TX)               // 19
#define NTY (HH / TY)               // 44
#define TILES (NTY * NTX)           // 836 per batch
#define NBLK (BB * TILES)           // 1672 = 8 * 209
#define CHUNK (NBLK / 8)            // 209
#define NTHR 512
#define HALO 7
#define SROWS (TY + 2 * HALO + 1)   // 23 raw rows
#define PROWS (SROWS - 1)           // 22 packed row-pair rows
#define SCOLS (TX + 2 * HALO + 2)   // 80
#define PN (PROWS * SCOLS)          // 1760 packed entries
#define NSTG ((PN + NTHR - 1) / NTHR)   // 4
#define NPAIR (PN / 2)              // 880 float4 slots
#define NPI ((NPAIR + NTHR - 1) / NTHR) // 2 interior iterations

__global__ __launch_bounds__(NTHR, 6) void ppd_kernel(
    const float* __restrict__ depth,   // [B, H*W]
    const float* __restrict__ weight,  // [B, 9, H*W]
    const float* __restrict__ offset,  // [B, 18, H*W]
    const float* __restrict__ wk,      // [9]
    const float* __restrict__ bias,    // [1]
    float* __restrict__ out)           // [B, H*W]
{
    constexpr int HW = HH * WW;

    __shared__ float2 pd[PN];           // 14080 B

    // bijective XCD-chunked swizzle (1672 % 8 == 0)
    const int bid0 = blockIdx.x;
    const int bid  = (bid0 & 7) * CHUNK + (bid0 >> 3);

    const int b   = bid / TILES;
    const int rem = bid - b * TILES;
    const int ty  = rem / NTX;
    const int tx  = rem - ty * NTX;

    const int tid = threadIdx.x;
    const int lx  = tid & (TX - 1);
    const int lyq = tid >> 6;             // 0..7
    const int x   = tx * TX + lx;
    const int y   = ty * TY + lyq;

    const float* dimg = depth + (size_t)b * HW;
    const int base_y = ty * TY - HALO;
    const int base_x = tx * TX - HALO;

    // interior: all raw rows [base_y, base_y+22] and cols [base_x, base_x+79]
    // in-image. base_y >= 0 <=> ty >= 1; base_y+22 <= 351 <=> ty <= 42.
    const bool interior = (ty >= 1) & (ty <= 42) & (tx >= 1) & (tx <= 17);

    // ---- staging phase A: global loads to registers ----
    float2 fa[NPI], fb[NPI];            // interior regs
    float2 stg[NSTG];                   // boundary regs
    if (interior) {
#pragma unroll
        for (int i = 0; i < NPI; ++i) {
            const int s = tid + i * NTHR;       // pair-slot 0..879
            const int e = 2 * s;                // even entry
            const int r = e / SCOLS;
            const int c = e - r * SCOLS;
            const float* p0 = dimg + (base_y + r)     * WW + base_x + c;
            const float* p1 = dimg + (base_y + r + 1) * WW + base_x + c;
            if (s < NPAIR) {
                __builtin_memcpy(&fa[i], p0, 8);
                __builtin_memcpy(&fb[i], p1, 8);
            }
        }
    } else {
#pragma unroll
        for (int i = 0; i < NSTG; ++i) {
            const int t = tid + i * NTHR;
            const int r = t / SCOLS;
            const int c = t - r * SCOLS;
            const int gy = base_y + r;
            const int gx = base_x + c;
            float a = 0.f, bb2 = 0.f;
            const bool gxok = ((unsigned)gx < (unsigned)WW) && (t < PN);
            if (gxok && (unsigned)gy < (unsigned)HH)       a   = dimg[gy * WW + gx];
            if (gxok && (unsigned)(gy + 1) < (unsigned)HH) bb2 = dimg[(gy + 1) * WW + gx];
            stg[i] = make_float2(a, bb2);
        }
    }

    // ---- streaming plane loads (single-use -> nontemporal) ----
    const int hw = y * WW + x;
    const float* wgt = weight + (size_t)b * (K2 * HW) + hw;
    const float* off = offset + (size_t)b * (2 * K2 * HW) + hw;

    float dyv[K2], dxv[K2], wv[K2];
#pragma unroll
    for (int k = 0; k < K2; ++k) {
        dyv[k] = __builtin_nontemporal_load(&off[(2 * k)     * HW]);
        dxv[k] = __builtin_nontemporal_load(&off[(2 * k + 1) * HW]);
    }
#pragma unroll
    for (int k = 0; k < K2; ++k) wv[k] = __builtin_nontemporal_load(&wgt[k * HW]);

    // ---- staging phase B: LDS writes (waits staging loads only) ----
    if (interior) {
#pragma unroll
        for (int i = 0; i < NPI; ++i) {
            const int s = tid + i * NTHR;
            if (s < NPAIR) {
                float4 q = make_float4(fa[i].x, fb[i].x, fa[i].y, fb[i].y);
                *reinterpret_cast<float4*>(&pd[2 * s]) = q;
            }
        }
    } else {
#pragma unroll
        for (int i = 0; i < NSTG; ++i) {
            const int t = tid + i * NTHR;
            if (t < PN) pd[t] = stg[i];
        }
    }

    // ---- PRE-BARRIER: tap addresses + fracs + miss bits + wsum ----
    int   ta[K2];
    float fyv[K2], fxv[K2];
    unsigned miss = 0u;
#pragma unroll
    for (int k = 0; k < K2; ++k) {
        const int kh = k / KK;
        const int kw = k - kh * KK;
        const float py = (float)(y - PAD + kh) + dyv[k];
        const float px = (float)(x - PAD + kw) + dxv[k];
        const float y0f = floorf(py);
        const float x0f = floorf(px);
        fyv[k] = py - y0f;
        fxv[k] = px - x0f;
        const int y0 = (int)y0f;
        const int x0 = (int)x0f;
        const int lr = y0 - base_y;
        const int lc = x0 - base_x;
        const int lrc = min(max(lr, 0), PROWS - 1);
        const int lcc = min(max(lc, 0), SCOLS - 2);
        const bool ok = ((unsigned)lr <= (unsigned)(PROWS - 1)) &
                        ((unsigned)lc <= (unsigned)(SCOLS - 2));
        miss |= ok ? 0u : (1u << k);
        ta[k] = lrc * SCOLS + lcc;
    }

    float wsum = 0.f;
#pragma unroll
    for (int k = 0; k < K2; ++k) wsum += wv[k];
    const float wmean = wsum * (1.0f / 9.0f);

    __syncthreads();

    // ---- POST-BARRIER: all corner-pair reads back-to-back, then lerps ----
    float2 c0[K2], c1[K2];
#pragma unroll
    for (int k = 0; k < K2; ++k) {
        c0[k] = pd[ta[k]];          // (v00, v10)
        c1[k] = pd[ta[k] + 1];      // (v01, v11)
    }

    float acc = 0.f;
#pragma unroll
    for (int k = 0; k < K2; ++k) {
        const float fy = fyv[k];
        const float fx = fxv[k];
        const float s = (1.f - fy) * ((1.f - fx) * c0[k].x + fx * c1[k].x)
                      + fy         * ((1.f - fx) * c0[k].y + fx * c1[k].y);
        acc = fmaf(wk[k] * (wv[k] - wmean), s, acc);
    }

    // ---- rare exact fixup for taps outside the staged halo ----
    if (miss) {
#pragma unroll 1
        for (int k = 0; k < K2; ++k) {
            if (!(miss & (1u << k))) continue;
            const int kh = k / KK;
            const int kw = k - kh * KK;
            const float dy = off[(2 * k)     * HW];
            const float dx = off[(2 * k + 1) * HW];
            const float wvk = wgt[k * HW];
            const float py = (float)(y - PAD + kh) + dy;
            const float px = (float)(x - PAD + kw) + dx;
            const float y0f = floorf(py);
            const float x0f = floorf(px);
            const float fy = py - y0f;
            const float fx = px - x0f;
            const int y0 = (int)y0f;
            const int x0 = (int)x0f;

            // recompute the (wrong) fast-path sample exactly as above
            const int lrc = min(max(y0 - base_y, 0), PROWS - 1);
            const int lcc = min(max(x0 - base_x, 0), SCOLS - 2);
            const float2 e0 = pd[lrc * SCOLS + lcc];
            const float2 e1 = pd[lrc * SCOLS + lcc + 1];
            const float sf = (1.f - fy) * ((1.f - fx) * e0.x + fx * e1.x)
                           + fy         * ((1.f - fx) * e0.y + fx * e1.y);

            // true sample via global clamped loads + validity-folded weights
            const float wy0 = ((unsigned)y0       < (unsigned)HH) ? (1.f - fy) : 0.f;
            const float wy1 = ((unsigned)(y0 + 1) < (unsigned)HH) ? fy         : 0.f;
            const float wx0 = ((unsigned)x0       < (unsigned)WW) ? (1.f - fx) : 0.f;
            const float wx1 = ((unsigned)(x0 + 1) < (unsigned)WW) ? fx         : 0.f;
            const int y0c = min(max(y0, 0), HH - 1);
            const int y1c = min(max(y0 + 1, 0), HH - 1);
            const int x0c = min(max(x0, 0), WW - 1);
            const int x1c = min(max(x0 + 1, 0), WW - 1);
            const float st = wy0 * (wx0 * dimg[y0c * WW + x0c] + wx1 * dimg[y0c * WW + x1c])
                           + wy1 * (wx0 * dimg[y1c * WW + x0c] + wx1 * dimg[y1c * WW + x1c]);

            acc = fmaf(wk[k] * (wvk - wmean), st - sf, acc);
        }
    }

    // residual from LDS; epilogue (nontemporal store — single-use)
    const float dres = pd[(y - base_y) * SCOLS + (x - base_x)].x;
    __builtin_nontemporal_store(acc + bias[0] + dres, &out[(size_t)b * HW + hw]);
}

extern "C" void kernel_launch(void* const* d_in, const int* in_sizes, int n_in,
                              void* d_out, int out_size, void* d_ws, size_t ws_size,
                              hipStream_t stream) {
    const float* depth  = (const float*)d_in[0];
    const float* weight = (const float*)d_in[1];
    const float* offset = (const float*)d_in[2];
    const float* wk     = (const float*)d_in[3];
    const float* bias   = (const float*)d_in[4];
    float* out = (float*)d_out;

    ppd_kernel<<<NBLK, NTHR, 0, stream>>>(depth, weight, offset, wk, bias, out);
}